// Round 4
// baseline (544.751 us; speedup 1.0000x reference)
//
#include <hip/hip_runtime.h>
#include <hip/hip_bf16.h>
#include <math.h>

#define H 512
#define S 65
#define HS (H * S)   // 33280
#define KS3 24       // linear3 K-slices (1536 / 64)
#define KS4 16       // linear4 K-slices (1024 / 64)

// All activations live in T-layout: X[s][h], row-major, contiguous over h.

// ---------------------------------------------------------------------------
// yT[s*H+h] = emb[h*S+s] * x[s]
// ---------------------------------------------------------------------------
__global__ void scale_embed_kernel(const float* __restrict__ inp,
                                   const float* __restrict__ emb,
                                   float* __restrict__ yT) {
    int i = blockIdx.x * blockDim.x + threadIdx.x;
    if (i < HS) {
        int s = i / H;
        int h = i % H;
        float x = (s == 64) ? 1.0f : inp[s];
        yT[i] = emb[h * S + s] * x;
    }
}

// ---------------------------------------------------------------------------
// Tiled KQV GEMM.  C[s][n] = sum_k yT[s][k] * W[n][k]
// Block: 256 thr.  Tile: all 65 s x 64 n, K-range 128 (K-split 4).
// grid.x = 8 n-tiles * 4 k-splits = 32;  grid.y = {k,q,v};  grid.z = head slot.
// W tile staged to LDS transposed with XOR swizzle (2-way conflicts max).
// Partials written to part[( (slot*3+which)*4 + kidx )*HS].
// ---------------------------------------------------------------------------
__global__ void kqv_gemm_tiled(const float* __restrict__ wq,
                               const float* __restrict__ wk,
                               const float* __restrict__ wv,
                               int layer, int head0,
                               const float* __restrict__ yT,
                               float* __restrict__ part) {
    int slot  = blockIdx.z;
    int which = blockIdx.y;          // 0->k, 1->q, 2->v
    int mat = layer * 3 + head0 + slot;
    const float* W = (which == 0 ? wk : (which == 1 ? wq : wv)) + (size_t)mat * H * H;

    int n0   = (blockIdx.x & 7) * 64;
    int kidx = blockIdx.x >> 3;      // 0..3

    __shared__ float Wt[64 * 64];    // [k][n-swizzled]
    __shared__ float As[65 * 64];    // [s][k]

    int t  = threadIdx.x;
    int nq = t & 15;                 // n = n0 + 4*nq
    int g  = t >> 4;                 // s-group: s = g + 16*r (+ s=64 for g==0)

    float4 acc[5];
#pragma unroll
    for (int r = 0; r < 5; ++r) acc[r] = make_float4(0.f, 0.f, 0.f, 0.f);

#pragma unroll
    for (int ch = 0; ch < 2; ++ch) {
        int kc0 = kidx * 128 + ch * 64;

        // ---- stage W tile (1024 float4), coalesced load, swizzled transpose store
#pragma unroll
        for (int c = 0; c < 4; ++c) {
            int f = c * 256 + t;
            int wn  = f >> 4;        // 0..63
            int kf4 = f & 15;        // 0..15 (k = 4*kf4 + j)
            float4 w4 = *(const float4*)(W + (size_t)(n0 + wn) * H + kc0 + 4 * kf4);
            int sw = ((wn >> 2) ^ (kf4 & 7));
            int base = (4 * kf4) * 64 + 4 * sw + (wn & 3);
            Wt[base      ] = w4.x;
            Wt[base +  64] = w4.y;
            Wt[base + 128] = w4.z;
            Wt[base + 192] = w4.w;
        }
        // ---- stage A tile (1040 float4)
#pragma unroll
        for (int c = 0; c < 5; ++c) {
            int f = c * 256 + t;
            if (f < 1040) {
                int as  = f >> 4;    // 0..64
                int kf4 = f & 15;
                float4 a4 = *(const float4*)(yT + (size_t)as * H + kc0 + 4 * kf4);
                *(float4*)(&As[as * 64 + 4 * kf4]) = a4;
            }
        }
        __syncthreads();

        // ---- compute
#pragma unroll
        for (int k4 = 0; k4 < 16; ++k4) {
            int swc = 4 * (nq ^ (k4 & 7));
            float4 w0 = *(const float4*)(&Wt[(4 * k4 + 0) * 64 + swc]);
            float4 w1 = *(const float4*)(&Wt[(4 * k4 + 1) * 64 + swc]);
            float4 w2 = *(const float4*)(&Wt[(4 * k4 + 2) * 64 + swc]);
            float4 w3 = *(const float4*)(&Wt[(4 * k4 + 3) * 64 + swc]);
#pragma unroll
            for (int r = 0; r < 4; ++r) {
                float4 a = *(const float4*)(&As[(g + 16 * r) * 64 + 4 * k4]);
                acc[r].x = fmaf(a.x, w0.x, acc[r].x);
                acc[r].y = fmaf(a.x, w0.y, acc[r].y);
                acc[r].z = fmaf(a.x, w0.z, acc[r].z);
                acc[r].w = fmaf(a.x, w0.w, acc[r].w);
                acc[r].x = fmaf(a.y, w1.x, acc[r].x);
                acc[r].y = fmaf(a.y, w1.y, acc[r].y);
                acc[r].z = fmaf(a.y, w1.z, acc[r].z);
                acc[r].w = fmaf(a.y, w1.w, acc[r].w);
                acc[r].x = fmaf(a.z, w2.x, acc[r].x);
                acc[r].y = fmaf(a.z, w2.y, acc[r].y);
                acc[r].z = fmaf(a.z, w2.z, acc[r].z);
                acc[r].w = fmaf(a.z, w2.w, acc[r].w);
                acc[r].x = fmaf(a.w, w3.x, acc[r].x);
                acc[r].y = fmaf(a.w, w3.y, acc[r].y);
                acc[r].z = fmaf(a.w, w3.z, acc[r].z);
                acc[r].w = fmaf(a.w, w3.w, acc[r].w);
            }
            if (g == 0) {
                float4 a = *(const float4*)(&As[64 * 64 + 4 * k4]);
                acc[4].x = fmaf(a.x, w0.x, acc[4].x);
                acc[4].y = fmaf(a.x, w0.y, acc[4].y);
                acc[4].z = fmaf(a.x, w0.z, acc[4].z);
                acc[4].w = fmaf(a.x, w0.w, acc[4].w);
                acc[4].x = fmaf(a.y, w1.x, acc[4].x);
                acc[4].y = fmaf(a.y, w1.y, acc[4].y);
                acc[4].z = fmaf(a.y, w1.z, acc[4].z);
                acc[4].w = fmaf(a.y, w1.w, acc[4].w);
                acc[4].x = fmaf(a.z, w2.x, acc[4].x);
                acc[4].y = fmaf(a.z, w2.y, acc[4].y);
                acc[4].z = fmaf(a.z, w2.z, acc[4].z);
                acc[4].w = fmaf(a.z, w2.w, acc[4].w);
                acc[4].x = fmaf(a.w, w3.x, acc[4].x);
                acc[4].y = fmaf(a.w, w3.y, acc[4].y);
                acc[4].z = fmaf(a.w, w3.z, acc[4].z);
                acc[4].w = fmaf(a.w, w3.w, acc[4].w);
            }
        }
        __syncthreads();
    }

    float* P = part + (size_t)((slot * 3 + which) * 4 + kidx) * HS;
#pragma unroll
    for (int r = 0; r < 4; ++r) {
        *(float4*)(P + (size_t)(g + 16 * r) * H + n0 + 4 * nq) = acc[r];
    }
    if (g == 0) {
        *(float4*)(P + (size_t)64 * H + n0 + 4 * nq) = acc[4];
    }
}

// ---------------------------------------------------------------------------
// Sum the 4 K-split partials into kT/qT/vT.
// grid (130, 3, slots)
// ---------------------------------------------------------------------------
__global__ void kqv_combine_kernel(const float* __restrict__ part,
                                   float* __restrict__ kT,
                                   float* __restrict__ qT,
                                   float* __restrict__ vT) {
    int slot  = blockIdx.z;
    int which = blockIdx.y;
    int i = blockIdx.x * 256 + threadIdx.x;
    float* out = (which == 0 ? kT : (which == 1 ? qT : vT)) + (size_t)slot * HS;
    const float* P = part + (size_t)((slot * 3 + which) * 4) * HS;
    out[i] = (P[i] + P[HS + i]) + (P[2 * HS + i] + P[3 * HS + i]);
}

// ---------------------------------------------------------------------------
// Attention, one block (64 threads) per (row a, head slot).
// ---------------------------------------------------------------------------
__global__ void attn_kernel(const float* __restrict__ kT,
                            const float* __restrict__ qT,
                            const float* __restrict__ vT,
                            float* __restrict__ att, int a_offset) {
    int a = blockIdx.x + a_offset;
    int slot = blockIdx.y;
    int tid = threadIdx.x;   // 64

    const float* kk = kT + (size_t)slot * HS;
    const float* qq = qT + (size_t)slot * HS;
    const float* vv = vT + (size_t)slot * HS;
    float* ao = att + (size_t)slot * S * H;

    __shared__ float sm[S];
    __shared__ float p[S];

    const float4* ka = (const float4*)(kk + (size_t)a * H);   // broadcast
    for (int b = tid; b < S; b += 64) {
        const float4* qb = (const float4*)(qq + (size_t)b * H);
        float4 c0 = {0,0,0,0}, c1 = {0,0,0,0}, c2 = {0,0,0,0}, c3 = {0,0,0,0};
        for (int t = 0; t < H / 4; t += 4) {
            float4 k0 = ka[t+0], k1 = ka[t+1], k2 = ka[t+2], k3 = ka[t+3];
            float4 q0 = qb[t+0], q1 = qb[t+1], q2 = qb[t+2], q3 = qb[t+3];
            c0.x = fmaf(k0.x, q0.x, c0.x); c0.y = fmaf(k0.y, q0.y, c0.y);
            c0.z = fmaf(k0.z, q0.z, c0.z); c0.w = fmaf(k0.w, q0.w, c0.w);
            c1.x = fmaf(k1.x, q1.x, c1.x); c1.y = fmaf(k1.y, q1.y, c1.y);
            c1.z = fmaf(k1.z, q1.z, c1.z); c1.w = fmaf(k1.w, q1.w, c1.w);
            c2.x = fmaf(k2.x, q2.x, c2.x); c2.y = fmaf(k2.y, q2.y, c2.y);
            c2.z = fmaf(k2.z, q2.z, c2.z); c2.w = fmaf(k2.w, q2.w, c2.w);
            c3.x = fmaf(k3.x, q3.x, c3.x); c3.y = fmaf(k3.y, q3.y, c3.y);
            c3.z = fmaf(k3.z, q3.z, c3.z); c3.w = fmaf(k3.w, q3.w, c3.w);
        }
        sm[b] = ((c0.x + c0.y) + (c0.z + c0.w)) + ((c1.x + c1.y) + (c1.z + c1.w))
              + ((c2.x + c2.y) + (c2.z + c2.w)) + ((c3.x + c3.y) + (c3.z + c3.w));
    }
    __syncthreads();

    float maxv = -INFINITY;
    for (int i = 0; i < S; ++i) maxv = fmaxf(maxv, sm[i]);
    float sum = 0.0f;
    for (int i = 0; i < S; ++i) sum += expf(sm[i] - maxv);
    float inv = 1.0f / sum;
    for (int b = tid; b < S; b += 64) {
        p[b] = expf(sm[b] - maxv) * inv;
    }
    __syncthreads();

    for (int hh = tid; hh < H; hh += 64) {
        float a0 = 0.f, a1 = 0.f, a2 = 0.f, a3 = 0.f;
        for (int b = 0; b < 64; b += 4) {
            a0 = fmaf(p[b + 0], vv[(b + 0) * H + hh], a0);
            a1 = fmaf(p[b + 1], vv[(b + 1) * H + hh], a1);
            a2 = fmaf(p[b + 2], vv[(b + 2) * H + hh], a2);
            a3 = fmaf(p[b + 3], vv[(b + 3) * H + hh], a3);
        }
        a0 = fmaf(p[64], vv[64 * H + hh], a0);
        ao[(size_t)a * H + hh] = (a0 + a1) + (a2 + a3);
    }
}

// ---------------------------------------------------------------------------
// K-split partials of: yT[s*H+h] = relu( sum_j cat[s,j]*lin[j,h] )
// ---------------------------------------------------------------------------
__global__ void linear_partial_kernel(const float* __restrict__ attA,
                                      const float* __restrict__ attB,
                                      const float* __restrict__ attC,
                                      const float* __restrict__ lin,
                                      float* __restrict__ part) {
    int seg = blockIdx.y;
    const float* att = (seg < 2) ? attA : (seg < 4 ? attB : attC);
    int i = blockIdx.x * blockDim.x + threadIdx.x;
    if (i >= HS) return;
    int s = i / H;
    int h = i % H;

    const float* row = att + (size_t)s * H + (seg & 1) * 256;  // broadcast
    const float* L = lin + (size_t)(seg * 256) * H + h;        // coalesced

    float a0 = 0.f, a1 = 0.f, a2 = 0.f, a3 = 0.f;
    for (int j = 0; j < 256; j += 4) {
        a0 = fmaf(row[j + 0], L[(size_t)(j + 0) * H], a0);
        a1 = fmaf(row[j + 1], L[(size_t)(j + 1) * H], a1);
        a2 = fmaf(row[j + 2], L[(size_t)(j + 2) * H], a2);
        a3 = fmaf(row[j + 3], L[(size_t)(j + 3) * H], a3);
    }
    part[(size_t)seg * HS + i] = (a0 + a1) + (a2 + a3);
}

__global__ void combine_relu_kernel(const float* __restrict__ part,
                                    float* __restrict__ yT) {
    int i = blockIdx.x * blockDim.x + threadIdx.x;
    if (i >= HS) return;
    float s = part[i] + part[HS + i] + part[2 * HS + i]
            + part[3 * HS + i] + part[4 * HS + i] + part[5 * HS + i];
    yT[i] = fmaxf(s, 0.0f);
}

// ---------------------------------------------------------------------------
// Final stage
// ---------------------------------------------------------------------------
__global__ void lin3_partial_kernel(const float* __restrict__ attA,
                                    const float* __restrict__ attB,
                                    const float* __restrict__ attC,
                                    const float* __restrict__ lin3,
                                    float* __restrict__ tpart) {
    int j2 = blockIdx.x * 256 + threadIdx.x;   // [0, 1024)
    int ks = blockIdx.y;                       // [0, 24)
    const float* row = (ks < 8) ? (attA + (size_t)64 * H)
                     : (ks < 16 ? (attB + (size_t)64 * H)
                                : (attC + (size_t)64 * H));
    int j0 = (ks & 7) * 64;
    int jbase = ks * 64;

    float a0 = 0.f, a1 = 0.f, a2 = 0.f, a3 = 0.f;
    for (int j = 0; j < 64; j += 4) {
        a0 = fmaf(row[j0 + j + 0], lin3[(size_t)(jbase + j + 0) * 1024 + j2], a0);
        a1 = fmaf(row[j0 + j + 1], lin3[(size_t)(jbase + j + 1) * 1024 + j2], a1);
        a2 = fmaf(row[j0 + j + 2], lin3[(size_t)(jbase + j + 2) * 1024 + j2], a2);
        a3 = fmaf(row[j0 + j + 3], lin3[(size_t)(jbase + j + 3) * 1024 + j2], a3);
    }
    tpart[ks * 1024 + j2] = (a0 + a1) + (a2 + a3);
}

__global__ void lin4_partial_kernel(const float* __restrict__ tpart,
                                    const float* __restrict__ lin4,
                                    float* __restrict__ upart) {
    __shared__ float tl[64];
    int hh = blockIdx.x * 256 + threadIdx.x;   // [0, 512)
    int ks = blockIdx.y;                       // [0, 16)
    int j2base = ks * 64;

    if (threadIdx.x < 64) {
        int j2 = j2base + threadIdx.x;
        float s = 0.f;
#pragma unroll
        for (int p = 0; p < KS3; ++p) s += tpart[p * 1024 + j2];
        tl[threadIdx.x] = fmaxf(s, 0.f);
    }
    __syncthreads();

    float a0 = 0.f, a1 = 0.f, a2 = 0.f, a3 = 0.f;
    for (int j = 0; j < 64; j += 4) {
        a0 = fmaf(tl[j + 0], lin4[(size_t)(j2base + j + 0) * H + hh], a0);
        a1 = fmaf(tl[j + 1], lin4[(size_t)(j2base + j + 1) * H + hh], a1);
        a2 = fmaf(tl[j + 2], lin4[(size_t)(j2base + j + 2) * H + hh], a2);
        a3 = fmaf(tl[j + 3], lin4[(size_t)(j2base + j + 3) * H + hh], a3);
    }
    upart[ks * H + hh] = (a0 + a1) + (a2 + a3);
}

__global__ void final_out_kernel(const float* __restrict__ upart,
                                 const float* __restrict__ lin5,
                                 float* __restrict__ out) {
    __shared__ float u[H];
    __shared__ float pr[8][64];
    int tid = threadIdx.x;   // 512

    {
        float s = 0.f;
#pragma unroll
        for (int p = 0; p < KS4; ++p) s += upart[p * H + tid];
        u[tid] = tanhf(s);
    }
    __syncthreads();

    int o  = tid & 63;
    int sl = tid >> 6;
    float acc = 0.f;
    int h0 = sl * 64;
#pragma unroll 8
    for (int j = 0; j < 64; ++j) {
        acc = fmaf(u[h0 + j], lin5[(h0 + j) * 64 + o], acc);
    }
    pr[sl][o] = acc;
    __syncthreads();

    if (tid < 64) {
        float s = 0.f;
#pragma unroll
        for (int p = 0; p < 8; ++p) s += pr[p][tid];
        out[tid] = s;
    }
}

// ---------------------------------------------------------------------------
extern "C" void kernel_launch(void* const* d_in, const int* in_sizes, int n_in,
                              void* d_out, int out_size, void* d_ws, size_t ws_size,
                              hipStream_t stream) {
    const float* inputs  = (const float*)d_in[0];
    const float* emb     = (const float*)d_in[1];
    const float* wq      = (const float*)d_in[2];
    const float* wk      = (const float*)d_in[3];
    const float* wv      = (const float*)d_in[4];
    const float* linear1 = (const float*)d_in[5];
    const float* linear2 = (const float*)d_in[6];
    const float* linear3 = (const float*)d_in[7];
    const float* linear4 = (const float*)d_in[8];
    const float* linear5 = (const float*)d_in[9];
    float* out = (float*)d_out;

    float* ws    = (float*)d_ws;
    float* y     = ws;                 // HS
    float* kT    = y     + HS;         // 3*HS
    float* qT    = kT    + 3 * HS;     // 3*HS
    float* vT    = qT    + 3 * HS;     // 3*HS
    float* att1  = vT    + 3 * HS;     // 3*HS
    float* att2  = att1  + 3 * HS;     // HS
    float* att3  = att2  + HS;         // HS
    float* part  = att3  + HS;         // 6*HS
    float* tpart = part  + 6 * HS;     // 24*1024
    float* upart = tpart + KS3 * 1024; // 16*512
    float* kqvp  = upart + KS4 * H;    // 36*HS  (kqv K-split partials)

    const int nb = HS / 256;           // 130

    scale_embed_kernel<<<nb, 256, 0, stream>>>(inputs, emb, y);

    // ---- Layer 1: all 3 heads ----
    kqv_gemm_tiled<<<dim3(32, 3, 3), 256, 0, stream>>>(wq, wk, wv, 0, 0, y, kqvp);
    kqv_combine_kernel<<<dim3(nb, 3, 3), 256, 0, stream>>>(kqvp, kT, qT, vT);
    attn_kernel<<<dim3(S, 3), 64, 0, stream>>>(kT, qT, vT, att1, 0);
    linear_partial_kernel<<<dim3(nb, 6), 256, 0, stream>>>(att1, att1 + HS, att1 + 2 * HS,
                                                           linear1, part);
    combine_relu_kernel<<<nb, 256, 0, stream>>>(part, y);

    // ---- Layer 2: only head 2 is consumed ----
    kqv_gemm_tiled<<<dim3(32, 3, 1), 256, 0, stream>>>(wq, wk, wv, 1, 2, y, kqvp);
    kqv_combine_kernel<<<dim3(nb, 3, 1), 256, 0, stream>>>(kqvp, kT, qT, vT);
    attn_kernel<<<dim3(S, 1), 64, 0, stream>>>(kT, qT, vT, att2, 0);
    linear_partial_kernel<<<dim3(nb, 6), 256, 0, stream>>>(att1, att1 + HS, att2,
                                                           linear2, part);
    combine_relu_kernel<<<nb, 256, 0, stream>>>(part, y);

    // ---- Layer 3: only head 2, and only row a=64 of its attention ----
    kqv_gemm_tiled<<<dim3(32, 3, 1), 256, 0, stream>>>(wq, wk, wv, 2, 2, y, kqvp);
    kqv_combine_kernel<<<dim3(nb, 3, 1), 256, 0, stream>>>(kqvp, kT, qT, vT);
    attn_kernel<<<dim3(1, 1), 64, 0, stream>>>(kT, qT, vT, att3, 64);

    // ---- Final stage ----
    lin3_partial_kernel<<<dim3(4, KS3), 256, 0, stream>>>(att1, att1 + HS, att3, linear3, tpart);
    lin4_partial_kernel<<<dim3(2, KS4), 256, 0, stream>>>(tpart, linear4, upart);
    final_out_kernel<<<1, 512, 0, stream>>>(upart, linear5, out);
}

// Round 5
// 264.459 us; speedup vs baseline: 2.0599x; 2.0599x over previous
//
#include <hip/hip_runtime.h>
#include <hip/hip_bf16.h>
#include <math.h>

#define H 512
#define S 65
#define SP 80                // padded s-dimension (rows 65..79 are zero)
#define HS (H * S)           // 33280
#define PHS (H * SP)         // 40960
#define KS3 24               // linear3 K-slices (1536 / 64)
#define KS4 16               // linear4 K-slices (1024 / 64)

// Activations: X[s][h] row-major, contiguous over h. yT / kT / qT / vT are
// SP-padded (pad rows zero); att buffers are S-rows (unpadded).

// ---------------------------------------------------------------------------
// yT[s*H+h] = emb[h*S+s] * x[s]  for s<65;  0 for pad rows.
// ---------------------------------------------------------------------------
__global__ void scale_embed_kernel(const float* __restrict__ inp,
                                   const float* __restrict__ emb,
                                   float* __restrict__ yT) {
    int i = blockIdx.x * blockDim.x + threadIdx.x;
    if (i < PHS) {
        int s = i / H;
        int h = i % H;
        float v = 0.0f;
        if (s < S) {
            float x = (s == 64) ? 1.0f : inp[s];
            v = emb[h * S + s] * x;
        }
        yT[i] = v;
    }
}

// ---------------------------------------------------------------------------
// Tiled KQV GEMM.  C[s][n] = sum_k yT[s][k] * W[n][k]
// Block: 256 thr. Tile: 80 s x 64 n, K-range 256 (K-split 2, 4 chunks of 64).
// grid.x = 8 n-tiles * 2 k-splits = 16; grid.y = {k,q,v}; grid.z = head slot.
// W tile staged to LDS transposed with XOR swizzle (<=2-way conflicts, free).
// Partials: part[((slot*3+which)*2 + kidx)*PHS].
// __launch_bounds__(256,2): up to 256 VGPRs -> no scratch spill (round-4 bug).
// ---------------------------------------------------------------------------
__global__ void __launch_bounds__(256, 2)
kqv_gemm_tiled(const float* __restrict__ wq,
               const float* __restrict__ wk,
               const float* __restrict__ wv,
               int layer, int head0,
               const float* __restrict__ yT,
               float* __restrict__ part) {
    int slot  = blockIdx.z;
    int which = blockIdx.y;          // 0->k, 1->q, 2->v
    int mat = layer * 3 + head0 + slot;
    const float* W = (which == 0 ? wk : (which == 1 ? wq : wv)) + (size_t)mat * H * H;

    int n0   = (blockIdx.x & 7) * 64;
    int kidx = blockIdx.x >> 3;      // 0..1

    __shared__ float Wt[64 * 64];    // [k-in-chunk][n swizzled]
    __shared__ float As[SP * 64];    // [s][k-in-chunk]

    int t  = threadIdx.x;
    int nq = t & 15;                 // n = n0 + 4*nq .. +3
    int g  = t >> 4;                 // s = g + 16*r, r<5

    float4 acc[5];
#pragma unroll
    for (int r = 0; r < 5; ++r) acc[r] = make_float4(0.f, 0.f, 0.f, 0.f);

    for (int ch = 0; ch < 4; ++ch) {
        int kc0 = kidx * 256 + ch * 64;

        // ---- stage W tile: 1024 float4, coalesced load, swizzled transpose
#pragma unroll
        for (int c = 0; c < 4; ++c) {
            int f = c * 256 + t;
            int wn  = f >> 4;        // 0..63
            int kf4 = f & 15;        // 0..15
            float4 w4 = *(const float4*)(W + (size_t)(n0 + wn) * H + kc0 + 4 * kf4);
            int sw = ((wn >> 2) ^ (kf4 & 7));
            int base = (4 * kf4) * 64 + 4 * sw + (wn & 3);
            Wt[base      ] = w4.x;
            Wt[base +  64] = w4.y;
            Wt[base + 128] = w4.z;
            Wt[base + 192] = w4.w;
        }
        // ---- stage A tile: 80*16 = 1280 float4, exactly 5 iters
#pragma unroll
        for (int c = 0; c < 5; ++c) {
            int f = c * 256 + t;
            int as  = f >> 4;        // 0..79
            int kf4 = f & 15;
            *(float4*)(&As[as * 64 + 4 * kf4]) =
                *(const float4*)(yT + (size_t)as * H + kc0 + 4 * kf4);
        }
        __syncthreads();

        // ---- compute
#pragma unroll
        for (int k4 = 0; k4 < 16; ++k4) {
            int swc = 4 * (nq ^ (k4 & 7));
            float4 w0 = *(const float4*)(&Wt[(4 * k4 + 0) * 64 + swc]);
            float4 w1 = *(const float4*)(&Wt[(4 * k4 + 1) * 64 + swc]);
            float4 w2 = *(const float4*)(&Wt[(4 * k4 + 2) * 64 + swc]);
            float4 w3 = *(const float4*)(&Wt[(4 * k4 + 3) * 64 + swc]);
#pragma unroll
            for (int r = 0; r < 5; ++r) {
                float4 a = *(const float4*)(&As[(g + 16 * r) * 64 + 4 * k4]);
                acc[r].x = fmaf(a.x, w0.x, acc[r].x);
                acc[r].y = fmaf(a.x, w0.y, acc[r].y);
                acc[r].z = fmaf(a.x, w0.z, acc[r].z);
                acc[r].w = fmaf(a.x, w0.w, acc[r].w);
                acc[r].x = fmaf(a.y, w1.x, acc[r].x);
                acc[r].y = fmaf(a.y, w1.y, acc[r].y);
                acc[r].z = fmaf(a.y, w1.z, acc[r].z);
                acc[r].w = fmaf(a.y, w1.w, acc[r].w);
                acc[r].x = fmaf(a.z, w2.x, acc[r].x);
                acc[r].y = fmaf(a.z, w2.y, acc[r].y);
                acc[r].z = fmaf(a.z, w2.z, acc[r].z);
                acc[r].w = fmaf(a.z, w2.w, acc[r].w);
                acc[r].x = fmaf(a.w, w3.x, acc[r].x);
                acc[r].y = fmaf(a.w, w3.y, acc[r].y);
                acc[r].z = fmaf(a.w, w3.z, acc[r].z);
                acc[r].w = fmaf(a.w, w3.w, acc[r].w);
            }
        }
        __syncthreads();
    }

    float* P = part + (size_t)((slot * 3 + which) * 2 + kidx) * PHS;
#pragma unroll
    for (int r = 0; r < 5; ++r) {
        *(float4*)(P + (size_t)(g + 16 * r) * H + n0 + 4 * nq) = acc[r];
    }
}

// ---------------------------------------------------------------------------
// Sum the 2 K-split partials into kT/qT/vT (PHS each). grid (160, 3, slots)
// ---------------------------------------------------------------------------
__global__ void kqv_combine_kernel(const float* __restrict__ part,
                                   float* __restrict__ kT,
                                   float* __restrict__ qT,
                                   float* __restrict__ vT) {
    int slot  = blockIdx.z;
    int which = blockIdx.y;
    int i = blockIdx.x * 256 + threadIdx.x;
    float* out = (which == 0 ? kT : (which == 1 ? qT : vT)) + (size_t)slot * PHS;
    const float* P = part + (size_t)((slot * 3 + which) * 2) * PHS;
    out[i] = P[i] + P[PHS + i];
}

// ---------------------------------------------------------------------------
// Attention, one block (64 threads) per (row a, head slot).
// ---------------------------------------------------------------------------
__global__ void attn_kernel(const float* __restrict__ kT,
                            const float* __restrict__ qT,
                            const float* __restrict__ vT,
                            float* __restrict__ att, int a_offset) {
    int a = blockIdx.x + a_offset;
    int slot = blockIdx.y;
    int tid = threadIdx.x;   // 64

    const float* kk = kT + (size_t)slot * PHS;
    const float* qq = qT + (size_t)slot * PHS;
    const float* vv = vT + (size_t)slot * PHS;
    float* ao = att + (size_t)slot * S * H;

    __shared__ float sm[S];
    __shared__ float p[S];

    const float4* ka = (const float4*)(kk + (size_t)a * H);   // broadcast
    for (int b = tid; b < S; b += 64) {
        const float4* qb = (const float4*)(qq + (size_t)b * H);
        float4 c0 = {0,0,0,0}, c1 = {0,0,0,0}, c2 = {0,0,0,0}, c3 = {0,0,0,0};
        for (int t = 0; t < H / 4; t += 4) {
            float4 k0 = ka[t+0], k1 = ka[t+1], k2 = ka[t+2], k3 = ka[t+3];
            float4 q0 = qb[t+0], q1 = qb[t+1], q2 = qb[t+2], q3 = qb[t+3];
            c0.x = fmaf(k0.x, q0.x, c0.x); c0.y = fmaf(k0.y, q0.y, c0.y);
            c0.z = fmaf(k0.z, q0.z, c0.z); c0.w = fmaf(k0.w, q0.w, c0.w);
            c1.x = fmaf(k1.x, q1.x, c1.x); c1.y = fmaf(k1.y, q1.y, c1.y);
            c1.z = fmaf(k1.z, q1.z, c1.z); c1.w = fmaf(k1.w, q1.w, c1.w);
            c2.x = fmaf(k2.x, q2.x, c2.x); c2.y = fmaf(k2.y, q2.y, c2.y);
            c2.z = fmaf(k2.z, q2.z, c2.z); c2.w = fmaf(k2.w, q2.w, c2.w);
            c3.x = fmaf(k3.x, q3.x, c3.x); c3.y = fmaf(k3.y, q3.y, c3.y);
            c3.z = fmaf(k3.z, q3.z, c3.z); c3.w = fmaf(k3.w, q3.w, c3.w);
        }
        sm[b] = ((c0.x + c0.y) + (c0.z + c0.w)) + ((c1.x + c1.y) + (c1.z + c1.w))
              + ((c2.x + c2.y) + (c2.z + c2.w)) + ((c3.x + c3.y) + (c3.z + c3.w));
    }
    __syncthreads();

    float maxv = -INFINITY;
    for (int i = 0; i < S; ++i) maxv = fmaxf(maxv, sm[i]);
    float sum = 0.0f;
    for (int i = 0; i < S; ++i) sum += expf(sm[i] - maxv);
    float inv = 1.0f / sum;
    for (int b = tid; b < S; b += 64) {
        p[b] = expf(sm[b] - maxv) * inv;
    }
    __syncthreads();

    for (int hh = tid; hh < H; hh += 64) {
        float a0 = 0.f, a1 = 0.f, a2 = 0.f, a3 = 0.f;
        for (int b = 0; b < 64; b += 4) {
            a0 = fmaf(p[b + 0], vv[(b + 0) * H + hh], a0);
            a1 = fmaf(p[b + 1], vv[(b + 1) * H + hh], a1);
            a2 = fmaf(p[b + 2], vv[(b + 2) * H + hh], a2);
            a3 = fmaf(p[b + 3], vv[(b + 3) * H + hh], a3);
        }
        a0 = fmaf(p[64], vv[64 * H + hh], a0);
        ao[(size_t)a * H + hh] = (a0 + a1) + (a2 + a3);
    }
}

// ---------------------------------------------------------------------------
// K-split partials of: yT[s*H+h] = relu( sum_j cat[s,j]*lin[j,h] )
// ---------------------------------------------------------------------------
__global__ void linear_partial_kernel(const float* __restrict__ attA,
                                      const float* __restrict__ attB,
                                      const float* __restrict__ attC,
                                      const float* __restrict__ lin,
                                      float* __restrict__ part) {
    int seg = blockIdx.y;
    const float* att = (seg < 2) ? attA : (seg < 4 ? attB : attC);
    int i = blockIdx.x * blockDim.x + threadIdx.x;
    if (i >= HS) return;
    int s = i / H;
    int h = i % H;

    const float* row = att + (size_t)s * H + (seg & 1) * 256;  // broadcast
    const float* L = lin + (size_t)(seg * 256) * H + h;        // coalesced

    float a0 = 0.f, a1 = 0.f, a2 = 0.f, a3 = 0.f;
    for (int j = 0; j < 256; j += 4) {
        a0 = fmaf(row[j + 0], L[(size_t)(j + 0) * H], a0);
        a1 = fmaf(row[j + 1], L[(size_t)(j + 1) * H], a1);
        a2 = fmaf(row[j + 2], L[(size_t)(j + 2) * H], a2);
        a3 = fmaf(row[j + 3], L[(size_t)(j + 3) * H], a3);
    }
    part[(size_t)seg * HS + i] = (a0 + a1) + (a2 + a3);
}

// Writes rows s<65 of yT (pad rows stay zero from scale_embed).
__global__ void combine_relu_kernel(const float* __restrict__ part,
                                    float* __restrict__ yT) {
    int i = blockIdx.x * blockDim.x + threadIdx.x;
    if (i >= HS) return;
    float s = part[i] + part[HS + i] + part[2 * HS + i]
            + part[3 * HS + i] + part[4 * HS + i] + part[5 * HS + i];
    yT[i] = fmaxf(s, 0.0f);
}

// ---------------------------------------------------------------------------
// Final stage
// ---------------------------------------------------------------------------
__global__ void lin3_partial_kernel(const float* __restrict__ attA,
                                    const float* __restrict__ attB,
                                    const float* __restrict__ attC,
                                    const float* __restrict__ lin3,
                                    float* __restrict__ tpart) {
    int j2 = blockIdx.x * 256 + threadIdx.x;   // [0, 1024)
    int ks = blockIdx.y;                       // [0, 24)
    const float* row = (ks < 8) ? (attA + (size_t)64 * H)
                     : (ks < 16 ? (attB + (size_t)64 * H)
                                : (attC + (size_t)64 * H));
    int j0 = (ks & 7) * 64;
    int jbase = ks * 64;

    float a0 = 0.f, a1 = 0.f, a2 = 0.f, a3 = 0.f;
    for (int j = 0; j < 64; j += 4) {
        a0 = fmaf(row[j0 + j + 0], lin3[(size_t)(jbase + j + 0) * 1024 + j2], a0);
        a1 = fmaf(row[j0 + j + 1], lin3[(size_t)(jbase + j + 1) * 1024 + j2], a1);
        a2 = fmaf(row[j0 + j + 2], lin3[(size_t)(jbase + j + 2) * 1024 + j2], a2);
        a3 = fmaf(row[j0 + j + 3], lin3[(size_t)(jbase + j + 3) * 1024 + j2], a3);
    }
    tpart[ks * 1024 + j2] = (a0 + a1) + (a2 + a3);
}

__global__ void lin4_partial_kernel(const float* __restrict__ tpart,
                                    const float* __restrict__ lin4,
                                    float* __restrict__ upart) {
    __shared__ float tl[64];
    int hh = blockIdx.x * 256 + threadIdx.x;   // [0, 512)
    int ks = blockIdx.y;                       // [0, 16)
    int j2base = ks * 64;

    if (threadIdx.x < 64) {
        int j2 = j2base + threadIdx.x;
        float s = 0.f;
#pragma unroll
        for (int p = 0; p < KS3; ++p) s += tpart[p * 1024 + j2];
        tl[threadIdx.x] = fmaxf(s, 0.f);
    }
    __syncthreads();

    float a0 = 0.f, a1 = 0.f, a2 = 0.f, a3 = 0.f;
    for (int j = 0; j < 64; j += 4) {
        a0 = fmaf(tl[j + 0], lin4[(size_t)(j2base + j + 0) * H + hh], a0);
        a1 = fmaf(tl[j + 1], lin4[(size_t)(j2base + j + 1) * H + hh], a1);
        a2 = fmaf(tl[j + 2], lin4[(size_t)(j2base + j + 2) * H + hh], a2);
        a3 = fmaf(tl[j + 3], lin4[(size_t)(j2base + j + 3) * H + hh], a3);
    }
    upart[ks * H + hh] = (a0 + a1) + (a2 + a3);
}

__global__ void final_out_kernel(const float* __restrict__ upart,
                                 const float* __restrict__ lin5,
                                 float* __restrict__ out) {
    __shared__ float u[H];
    __shared__ float pr[8][64];
    int tid = threadIdx.x;   // 512

    {
        float s = 0.f;
#pragma unroll
        for (int p = 0; p < KS4; ++p) s += upart[p * H + tid];
        u[tid] = tanhf(s);
    }
    __syncthreads();

    int o  = tid & 63;
    int sl = tid >> 6;
    float acc = 0.f;
    int h0 = sl * 64;
#pragma unroll 8
    for (int j = 0; j < 64; ++j) {
        acc = fmaf(u[h0 + j], lin5[(h0 + j) * 64 + o], acc);
    }
    pr[sl][o] = acc;
    __syncthreads();

    if (tid < 64) {
        float s = 0.f;
#pragma unroll
        for (int p = 0; p < 8; ++p) s += pr[p][tid];
        out[tid] = s;
    }
}

// ---------------------------------------------------------------------------
extern "C" void kernel_launch(void* const* d_in, const int* in_sizes, int n_in,
                              void* d_out, int out_size, void* d_ws, size_t ws_size,
                              hipStream_t stream) {
    const float* inputs  = (const float*)d_in[0];
    const float* emb     = (const float*)d_in[1];
    const float* wq      = (const float*)d_in[2];
    const float* wk      = (const float*)d_in[3];
    const float* wv      = (const float*)d_in[4];
    const float* linear1 = (const float*)d_in[5];
    const float* linear2 = (const float*)d_in[6];
    const float* linear3 = (const float*)d_in[7];
    const float* linear4 = (const float*)d_in[8];
    const float* linear5 = (const float*)d_in[9];
    float* out = (float*)d_out;

    float* ws    = (float*)d_ws;
    float* y     = ws;                  // PHS
    float* kT    = y     + PHS;         // 3*PHS
    float* qT    = kT    + 3 * PHS;     // 3*PHS
    float* vT    = qT    + 3 * PHS;     // 3*PHS
    float* att1  = vT    + 3 * PHS;     // 3*HS
    float* att2  = att1  + 3 * HS;      // HS
    float* att3  = att2  + HS;          // HS
    float* part  = att3  + HS;          // 6*HS
    float* tpart = part  + 6 * HS;      // 24*1024
    float* upart = tpart + KS3 * 1024;  // 16*512
    float* kqvp  = upart + KS4 * H;     // 18*PHS (kqv K-split partials)

    const int nb  = HS / 256;           // 130
    const int nbp = PHS / 256;          // 160

    scale_embed_kernel<<<nbp, 256, 0, stream>>>(inputs, emb, y);

    // ---- Layer 1: all 3 heads ----
    kqv_gemm_tiled<<<dim3(16, 3, 3), 256, 0, stream>>>(wq, wk, wv, 0, 0, y, kqvp);
    kqv_combine_kernel<<<dim3(nbp, 3, 3), 256, 0, stream>>>(kqvp, kT, qT, vT);
    attn_kernel<<<dim3(S, 3), 64, 0, stream>>>(kT, qT, vT, att1, 0);
    linear_partial_kernel<<<dim3(nb, 6), 256, 0, stream>>>(att1, att1 + HS, att1 + 2 * HS,
                                                           linear1, part);
    combine_relu_kernel<<<nb, 256, 0, stream>>>(part, y);

    // ---- Layer 2: only head 2 is consumed ----
    kqv_gemm_tiled<<<dim3(16, 3, 1), 256, 0, stream>>>(wq, wk, wv, 1, 2, y, kqvp);
    kqv_combine_kernel<<<dim3(nbp, 3, 1), 256, 0, stream>>>(kqvp, kT, qT, vT);
    attn_kernel<<<dim3(S, 1), 64, 0, stream>>>(kT, qT, vT, att2, 0);
    linear_partial_kernel<<<dim3(nb, 6), 256, 0, stream>>>(att1, att1 + HS, att2,
                                                           linear2, part);
    combine_relu_kernel<<<nb, 256, 0, stream>>>(part, y);

    // ---- Layer 3: only head 2, and only row a=64 of its attention ----
    kqv_gemm_tiled<<<dim3(16, 3, 1), 256, 0, stream>>>(wq, wk, wv, 2, 2, y, kqvp);
    kqv_combine_kernel<<<dim3(nbp, 3, 1), 256, 0, stream>>>(kqvp, kT, qT, vT);
    attn_kernel<<<dim3(1, 1), 64, 0, stream>>>(kT, qT, vT, att3, 64);

    // ---- Final stage ----
    lin3_partial_kernel<<<dim3(4, KS3), 256, 0, stream>>>(att1, att1 + HS, att3, linear3, tpart);
    lin4_partial_kernel<<<dim3(2, KS4), 256, 0, stream>>>(tpart, linear4, upart);
    final_out_kernel<<<1, 512, 0, stream>>>(upart, linear5, out);
}

// Round 6
// 262.242 us; speedup vs baseline: 2.0773x; 1.0085x over previous
//
#include <hip/hip_runtime.h>
#include <hip/hip_bf16.h>
#include <math.h>

#define H 512
#define S 65
#define SP 80                // padded s-dimension (rows 65..79 zero)
#define HS (H * S)           // 33280
#define PHS (H * SP)         // 40960
#define KS3 24               // linear3 K-slices (1536 / 64)
#define KS4 16               // linear4 K-slices (1024 / 64)

// Activations: X[s][h] row-major. yT is SP-padded (pad rows zero).
// kqv partials: part[((slot*3+which)*2 + kidx)*PHS], which: 0=k,1=q,2=v.

// ---------------------------------------------------------------------------
__global__ void scale_embed_kernel(const float* __restrict__ inp,
                                   const float* __restrict__ emb,
                                   float* __restrict__ yT) {
    int i = blockIdx.x * blockDim.x + threadIdx.x;
    if (i < PHS) {
        int s = i / H;
        int h = i % H;
        float v = 0.0f;
        if (s < S) {
            float x = (s == 64) ? 1.0f : inp[s];
            v = emb[h * S + s] * x;
        }
        yT[i] = v;
    }
}

// ---------------------------------------------------------------------------
// Tiled KQV GEMM (round-5 proven).  C[s][n] = sum_k yT[s][k] * W[n][k]
// grid.x = 8 n-tiles * 2 k-splits = 16; grid.y = {k,q,v}; grid.z = head slot.
// __launch_bounds__(256,2): no scratch spill (round-4 lesson: VGPR=64 cap).
// ---------------------------------------------------------------------------
__global__ void __launch_bounds__(256, 2)
kqv_gemm_tiled(const float* __restrict__ wq,
               const float* __restrict__ wk,
               const float* __restrict__ wv,
               int layer, int head0,
               const float* __restrict__ yT,
               float* __restrict__ part) {
    int slot  = blockIdx.z;
    int which = blockIdx.y;
    int mat = layer * 3 + head0 + slot;
    const float* W = (which == 0 ? wk : (which == 1 ? wq : wv)) + (size_t)mat * H * H;

    int n0   = (blockIdx.x & 7) * 64;
    int kidx = blockIdx.x >> 3;      // 0..1

    __shared__ float Wt[64 * 64];
    __shared__ float As[SP * 64];

    int t  = threadIdx.x;
    int nq = t & 15;
    int g  = t >> 4;

    float4 acc[5];
#pragma unroll
    for (int r = 0; r < 5; ++r) acc[r] = make_float4(0.f, 0.f, 0.f, 0.f);

    for (int ch = 0; ch < 4; ++ch) {
        int kc0 = kidx * 256 + ch * 64;

#pragma unroll
        for (int c = 0; c < 4; ++c) {
            int f = c * 256 + t;
            int wn  = f >> 4;
            int kf4 = f & 15;
            float4 w4 = *(const float4*)(W + (size_t)(n0 + wn) * H + kc0 + 4 * kf4);
            int sw = ((wn >> 2) ^ (kf4 & 7));
            int base = (4 * kf4) * 64 + 4 * sw + (wn & 3);
            Wt[base      ] = w4.x;
            Wt[base +  64] = w4.y;
            Wt[base + 128] = w4.z;
            Wt[base + 192] = w4.w;
        }
#pragma unroll
        for (int c = 0; c < 5; ++c) {
            int f = c * 256 + t;
            int as  = f >> 4;
            int kf4 = f & 15;
            *(float4*)(&As[as * 64 + 4 * kf4]) =
                *(const float4*)(yT + (size_t)as * H + kc0 + 4 * kf4);
        }
        __syncthreads();

#pragma unroll
        for (int k4 = 0; k4 < 16; ++k4) {
            int swc = 4 * (nq ^ (k4 & 7));
            float4 w0 = *(const float4*)(&Wt[(4 * k4 + 0) * 64 + swc]);
            float4 w1 = *(const float4*)(&Wt[(4 * k4 + 1) * 64 + swc]);
            float4 w2 = *(const float4*)(&Wt[(4 * k4 + 2) * 64 + swc]);
            float4 w3 = *(const float4*)(&Wt[(4 * k4 + 3) * 64 + swc]);
#pragma unroll
            for (int r = 0; r < 5; ++r) {
                float4 a = *(const float4*)(&As[(g + 16 * r) * 64 + 4 * k4]);
                acc[r].x = fmaf(a.x, w0.x, acc[r].x);
                acc[r].y = fmaf(a.x, w0.y, acc[r].y);
                acc[r].z = fmaf(a.x, w0.z, acc[r].z);
                acc[r].w = fmaf(a.x, w0.w, acc[r].w);
                acc[r].x = fmaf(a.y, w1.x, acc[r].x);
                acc[r].y = fmaf(a.y, w1.y, acc[r].y);
                acc[r].z = fmaf(a.y, w1.z, acc[r].z);
                acc[r].w = fmaf(a.y, w1.w, acc[r].w);
                acc[r].x = fmaf(a.z, w2.x, acc[r].x);
                acc[r].y = fmaf(a.z, w2.y, acc[r].y);
                acc[r].z = fmaf(a.z, w2.z, acc[r].z);
                acc[r].w = fmaf(a.z, w2.w, acc[r].w);
                acc[r].x = fmaf(a.w, w3.x, acc[r].x);
                acc[r].y = fmaf(a.w, w3.y, acc[r].y);
                acc[r].z = fmaf(a.w, w3.z, acc[r].z);
                acc[r].w = fmaf(a.w, w3.w, acc[r].w);
            }
        }
        __syncthreads();
    }

    float* P = part + (size_t)((slot * 3 + which) * 2 + kidx) * PHS;
#pragma unroll
    for (int r = 0; r < 5; ++r) {
        *(float4*)(P + (size_t)(g + 16 * r) * H + n0 + 4 * nq) = acc[r];
    }
}

// ---------------------------------------------------------------------------
// Attention with inline partial-combine. One block (256 thr) per (a, slot).
//   k/q/v = sum of the 2 K-split partials (read inline).
// ---------------------------------------------------------------------------
__global__ void attn_kernel(const float* __restrict__ kqvp,
                            float* __restrict__ att) {
    int a = blockIdx.x;
    int slot = blockIdx.y;
    int tid = threadIdx.x;   // 256

    const float* K0 = kqvp + (size_t)(slot * 3 + 0) * 2 * PHS;
    const float* K1 = K0 + PHS;
    const float* Q0 = kqvp + (size_t)(slot * 3 + 1) * 2 * PHS;
    const float* Q1 = Q0 + PHS;
    const float* V0 = kqvp + (size_t)(slot * 3 + 2) * 2 * PHS;
    const float* V1 = V0 + PHS;
    float* ao = att + (size_t)slot * S * H;

    __shared__ float ka[H];
    __shared__ float smv[S];
    __shared__ float p[S];

    // stage combined k-row a (coalesced)
    ka[tid]       = K0[(size_t)a * H + tid]       + K1[(size_t)a * H + tid];
    ka[tid + 256] = K0[(size_t)a * H + tid + 256] + K1[(size_t)a * H + tid + 256];
    __syncthreads();

    // scores: thread b<65 computes dot(ka, q_b)
    if (tid < S) {
        const float4* q0 = (const float4*)(Q0 + (size_t)tid * H);
        const float4* q1 = (const float4*)(Q1 + (size_t)tid * H);
        const float4* kl = (const float4*)ka;
        float4 c0 = {0,0,0,0}, c1 = {0,0,0,0};
        for (int t = 0; t < H / 4; t += 2) {
            float4 qa = q0[t],     qb = q1[t];
            float4 qc = q0[t + 1], qd = q1[t + 1];
            float4 k0 = kl[t], k1 = kl[t + 1];
            c0.x = fmaf(k0.x, qa.x + qb.x, c0.x);
            c0.y = fmaf(k0.y, qa.y + qb.y, c0.y);
            c0.z = fmaf(k0.z, qa.z + qb.z, c0.z);
            c0.w = fmaf(k0.w, qa.w + qb.w, c0.w);
            c1.x = fmaf(k1.x, qc.x + qd.x, c1.x);
            c1.y = fmaf(k1.y, qc.y + qd.y, c1.y);
            c1.z = fmaf(k1.z, qc.z + qd.z, c1.z);
            c1.w = fmaf(k1.w, qc.w + qd.w, c1.w);
        }
        smv[tid] = ((c0.x + c0.y) + (c0.z + c0.w)) + ((c1.x + c1.y) + (c1.z + c1.w));
    }
    __syncthreads();

    // softmax (redundant serial reduce over 65 — broadcast reads)
    float maxv = -INFINITY;
    for (int i = 0; i < S; ++i) maxv = fmaxf(maxv, smv[i]);
    float sum = 0.0f;
    for (int i = 0; i < S; ++i) sum += expf(smv[i] - maxv);
    float inv = 1.0f / sum;
    if (tid < S) p[tid] = expf(smv[tid] - maxv) * inv;
    __syncthreads();

    // PV: each thread 2 hh columns
#pragma unroll
    for (int rep = 0; rep < 2; ++rep) {
        int hh = tid + rep * 256;
        float a0 = 0.f, a1 = 0.f;
#pragma unroll 4
        for (int b = 0; b < 64; b += 2) {
            a0 = fmaf(p[b    ], V0[(size_t)(b    ) * H + hh] + V1[(size_t)(b    ) * H + hh], a0);
            a1 = fmaf(p[b + 1], V0[(size_t)(b + 1) * H + hh] + V1[(size_t)(b + 1) * H + hh], a1);
        }
        a0 = fmaf(p[64], V0[(size_t)64 * H + hh] + V1[(size_t)64 * H + hh], a0);
        ao[(size_t)a * H + hh] = a0 + a1;
    }
}

// ---------------------------------------------------------------------------
// Multi-segment linear partials (att1-dependent work, hoisted):
//   seg 0..5 : linear1 with [att1A|att1B|att1C]  -> part1[seg]
//   seg 6..9 : linear2 rows 0..1023 with att1A/att1B -> part2[seg-6]
// ---------------------------------------------------------------------------
__global__ void linA_kernel(const float* __restrict__ att1,
                            const float* __restrict__ lin1,
                            const float* __restrict__ lin2,
                            float* __restrict__ part1,
                            float* __restrict__ part2) {
    int seg = blockIdx.y;
    int i = blockIdx.x * blockDim.x + threadIdx.x;
    int s = i / H;
    int h = i % H;

    const float* att;
    const float* L;
    float* dst;
    if (seg < 6) {
        att = att1 + (size_t)(seg >> 1) * HS;
        L   = lin1 + (size_t)(seg * 256) * H + h;
        dst = part1 + (size_t)seg * HS;
    } else {
        int s2 = seg - 6;                       // 0..3
        att = att1 + (size_t)(s2 >> 1) * HS;    // A, A, B, B
        L   = lin2 + (size_t)(s2 * 256) * H + h;
        dst = part2 + (size_t)s2 * HS;
    }
    const float* row = att + (size_t)s * H + (seg & 1) * 256;

    float a0 = 0.f, a1 = 0.f, a2 = 0.f, a3 = 0.f;
    for (int j = 0; j < 256; j += 4) {
        a0 = fmaf(row[j + 0], L[(size_t)(j + 0) * H], a0);
        a1 = fmaf(row[j + 1], L[(size_t)(j + 1) * H], a1);
        a2 = fmaf(row[j + 2], L[(size_t)(j + 2) * H], a2);
        a3 = fmaf(row[j + 3], L[(size_t)(j + 3) * H], a3);
    }
    dst[i] = (a0 + a1) + (a2 + a3);
}

// lin2 rows 1024..1535 with att2 (segs 4,5) -> part2[4],[5]
__global__ void lin2c_kernel(const float* __restrict__ att2,
                             const float* __restrict__ lin2,
                             float* __restrict__ part2) {
    int seg = 4 + blockIdx.y;
    int i = blockIdx.x * blockDim.x + threadIdx.x;
    int s = i / H;
    int h = i % H;

    const float* row = att2 + (size_t)s * H + (seg & 1) * 256;
    const float* L = lin2 + (size_t)(seg * 256) * H + h;

    float a0 = 0.f, a1 = 0.f, a2 = 0.f, a3 = 0.f;
    for (int j = 0; j < 256; j += 4) {
        a0 = fmaf(row[j + 0], L[(size_t)(j + 0) * H], a0);
        a1 = fmaf(row[j + 1], L[(size_t)(j + 1) * H], a1);
        a2 = fmaf(row[j + 2], L[(size_t)(j + 2) * H], a2);
        a3 = fmaf(row[j + 3], L[(size_t)(j + 3) * H], a3);
    }
    part2[(size_t)seg * HS + i] = (a0 + a1) + (a2 + a3);
}

// 6-way sum + relu -> yT rows s<65 (pad rows stay zero)
__global__ void combine_relu_kernel(const float* __restrict__ part,
                                    float* __restrict__ yT) {
    int i = blockIdx.x * blockDim.x + threadIdx.x;
    if (i >= HS) return;
    float s = part[i] + part[HS + i] + part[2 * HS + i]
            + part[3 * HS + i] + part[4 * HS + i] + part[5 * HS + i];
    yT[i] = fmaxf(s, 0.0f);
}

// ---------------------------------------------------------------------------
// lin3 K-slices 0..15 (att1A/att1B rows 64) -> tpart[ks]
// ---------------------------------------------------------------------------
__global__ void lin3ab_kernel(const float* __restrict__ att1,
                              const float* __restrict__ lin3,
                              float* __restrict__ tpart) {
    int j2 = blockIdx.x * 256 + threadIdx.x;   // [0,1024)
    int ks = blockIdx.y;                       // [0,16)
    const float* row = att1 + (size_t)(ks >> 3) * HS + (size_t)64 * H;
    int j0 = (ks & 7) * 64;
    int jbase = ks * 64;

    float a0 = 0.f, a1 = 0.f, a2 = 0.f, a3 = 0.f;
    for (int j = 0; j < 64; j += 4) {
        a0 = fmaf(row[j0 + j + 0], lin3[(size_t)(jbase + j + 0) * 1024 + j2], a0);
        a1 = fmaf(row[j0 + j + 1], lin3[(size_t)(jbase + j + 1) * 1024 + j2], a1);
        a2 = fmaf(row[j0 + j + 2], lin3[(size_t)(jbase + j + 2) * 1024 + j2], a2);
        a3 = fmaf(row[j0 + j + 3], lin3[(size_t)(jbase + j + 3) * 1024 + j2], a3);
    }
    tpart[ks * 1024 + j2] = (a0 + a1) + (a2 + a3);
}

// ---------------------------------------------------------------------------
// Fused: layer-3 attention row 64 (head 2) + lin3 K-slices 16..23.
// grid (4, 8), 256 thr. Each block redundantly computes the row-64 softmax
// (tiny), the 64-col PV slice it needs, then its lin3 dot.
// ---------------------------------------------------------------------------
__global__ void attn3_lin3c_kernel(const float* __restrict__ kqvp,
                                   const float* __restrict__ lin3,
                                   float* __restrict__ tpart) {
    int tid = threadIdx.x;
    int ks  = 16 + blockIdx.y;                 // 16..23
    int j2  = blockIdx.x * 256 + tid;          // [0,1024)
    int j0  = (ks & 7) * 64;                   // att3 column offset

    const float* K0 = kqvp;
    const float* K1 = kqvp + PHS;
    const float* Q0 = kqvp + 2 * (size_t)PHS;
    const float* Q1 = kqvp + 3 * (size_t)PHS;
    const float* V0 = kqvp + 4 * (size_t)PHS;
    const float* V1 = kqvp + 5 * (size_t)PHS;

    __shared__ float ka[H];
    __shared__ float smv[S];
    __shared__ float p[S];
    __shared__ float att_s[64];

    ka[tid]       = K0[(size_t)64 * H + tid]       + K1[(size_t)64 * H + tid];
    ka[tid + 256] = K0[(size_t)64 * H + tid + 256] + K1[(size_t)64 * H + tid + 256];
    __syncthreads();

    if (tid < S) {
        const float4* q0 = (const float4*)(Q0 + (size_t)tid * H);
        const float4* q1 = (const float4*)(Q1 + (size_t)tid * H);
        const float4* kl = (const float4*)ka;
        float4 c0 = {0,0,0,0}, c1 = {0,0,0,0};
        for (int t = 0; t < H / 4; t += 2) {
            float4 qa = q0[t],     qb = q1[t];
            float4 qc = q0[t + 1], qd = q1[t + 1];
            float4 k0 = kl[t], k1 = kl[t + 1];
            c0.x = fmaf(k0.x, qa.x + qb.x, c0.x);
            c0.y = fmaf(k0.y, qa.y + qb.y, c0.y);
            c0.z = fmaf(k0.z, qa.z + qb.z, c0.z);
            c0.w = fmaf(k0.w, qa.w + qb.w, c0.w);
            c1.x = fmaf(k1.x, qc.x + qd.x, c1.x);
            c1.y = fmaf(k1.y, qc.y + qd.y, c1.y);
            c1.z = fmaf(k1.z, qc.z + qd.z, c1.z);
            c1.w = fmaf(k1.w, qc.w + qd.w, c1.w);
        }
        smv[tid] = ((c0.x + c0.y) + (c0.z + c0.w)) + ((c1.x + c1.y) + (c1.z + c1.w));
    }
    __syncthreads();

    float maxv = -INFINITY;
    for (int i = 0; i < S; ++i) maxv = fmaxf(maxv, smv[i]);
    float sum = 0.0f;
    for (int i = 0; i < S; ++i) sum += expf(smv[i] - maxv);
    float inv = 1.0f / sum;
    if (tid < S) p[tid] = expf(smv[tid] - maxv) * inv;
    __syncthreads();

    if (tid < 64) {
        int hh = j0 + tid;
        float a0 = 0.f, a1 = 0.f;
#pragma unroll 4
        for (int b = 0; b < 64; b += 2) {
            a0 = fmaf(p[b    ], V0[(size_t)(b    ) * H + hh] + V1[(size_t)(b    ) * H + hh], a0);
            a1 = fmaf(p[b + 1], V0[(size_t)(b + 1) * H + hh] + V1[(size_t)(b + 1) * H + hh], a1);
        }
        a0 = fmaf(p[64], V0[(size_t)64 * H + hh] + V1[(size_t)64 * H + hh], a0);
        att_s[tid] = a0 + a1;
    }
    __syncthreads();

    int jbase = ks * 64;
    float a0 = 0.f, a1 = 0.f, a2 = 0.f, a3 = 0.f;
    for (int j = 0; j < 64; j += 4) {
        a0 = fmaf(att_s[j + 0], lin3[(size_t)(jbase + j + 0) * 1024 + j2], a0);
        a1 = fmaf(att_s[j + 1], lin3[(size_t)(jbase + j + 1) * 1024 + j2], a1);
        a2 = fmaf(att_s[j + 2], lin3[(size_t)(jbase + j + 2) * 1024 + j2], a2);
        a3 = fmaf(att_s[j + 3], lin3[(size_t)(jbase + j + 3) * 1024 + j2], a3);
    }
    tpart[ks * 1024 + j2] = (a0 + a1) + (a2 + a3);
}

// ---------------------------------------------------------------------------
__global__ void lin4_partial_kernel(const float* __restrict__ tpart,
                                    const float* __restrict__ lin4,
                                    float* __restrict__ upart) {
    __shared__ float tl[64];
    int hh = blockIdx.x * 256 + threadIdx.x;   // [0,512)
    int ks = blockIdx.y;                       // [0,16)
    int j2base = ks * 64;

    if (threadIdx.x < 64) {
        int j2 = j2base + threadIdx.x;
        float s = 0.f;
#pragma unroll
        for (int p = 0; p < KS3; ++p) s += tpart[p * 1024 + j2];
        tl[threadIdx.x] = fmaxf(s, 0.f);
    }
    __syncthreads();

    float a0 = 0.f, a1 = 0.f, a2 = 0.f, a3 = 0.f;
    for (int j = 0; j < 64; j += 4) {
        a0 = fmaf(tl[j + 0], lin4[(size_t)(j2base + j + 0) * H + hh], a0);
        a1 = fmaf(tl[j + 1], lin4[(size_t)(j2base + j + 1) * H + hh], a1);
        a2 = fmaf(tl[j + 2], lin4[(size_t)(j2base + j + 2) * H + hh], a2);
        a3 = fmaf(tl[j + 3], lin4[(size_t)(j2base + j + 3) * H + hh], a3);
    }
    upart[ks * H + hh] = (a0 + a1) + (a2 + a3);
}

__global__ void final_out_kernel(const float* __restrict__ upart,
                                 const float* __restrict__ lin5,
                                 float* __restrict__ out) {
    __shared__ float u[H];
    __shared__ float pr[8][64];
    int tid = threadIdx.x;   // 512

    {
        float s = 0.f;
#pragma unroll
        for (int p = 0; p < KS4; ++p) s += upart[p * H + tid];
        u[tid] = tanhf(s);
    }
    __syncthreads();

    int o  = tid & 63;
    int sl = tid >> 6;
    float acc = 0.f;
    int h0 = sl * 64;
#pragma unroll 8
    for (int j = 0; j < 64; ++j) {
        acc = fmaf(u[h0 + j], lin5[(h0 + j) * 64 + o], acc);
    }
    pr[sl][o] = acc;
    __syncthreads();

    if (tid < 64) {
        float s = 0.f;
#pragma unroll
        for (int p = 0; p < 8; ++p) s += pr[p][tid];
        out[tid] = s;
    }
}

// ---------------------------------------------------------------------------
extern "C" void kernel_launch(void* const* d_in, const int* in_sizes, int n_in,
                              void* d_out, int out_size, void* d_ws, size_t ws_size,
                              hipStream_t stream) {
    const float* inputs  = (const float*)d_in[0];
    const float* emb     = (const float*)d_in[1];
    const float* wq      = (const float*)d_in[2];
    const float* wk      = (const float*)d_in[3];
    const float* wv      = (const float*)d_in[4];
    const float* linear1 = (const float*)d_in[5];
    const float* linear2 = (const float*)d_in[6];
    const float* linear3 = (const float*)d_in[7];
    const float* linear4 = (const float*)d_in[8];
    const float* linear5 = (const float*)d_in[9];
    float* out = (float*)d_out;

    float* ws    = (float*)d_ws;
    float* y     = ws;                  // PHS
    float* kqvp  = y     + PHS;         // 18*PHS
    float* att1  = kqvp  + 18 * PHS;    // 3*HS
    float* att2  = att1  + 3 * HS;      // HS
    float* part1 = att2  + HS;          // 6*HS
    float* part2 = part1 + 6 * HS;      // 6*HS
    float* tpart = part2 + 6 * HS;      // 24*1024
    float* upart = tpart + KS3 * 1024;  // 16*512

    const int nb  = HS / 256;           // 130
    const int nbp = PHS / 256;          // 160

    scale_embed_kernel<<<nbp, 256, 0, stream>>>(inputs, emb, y);

    // ---- Layer 1 ----
    kqv_gemm_tiled<<<dim3(16, 3, 3), 256, 0, stream>>>(wq, wk, wv, 0, 0, y, kqvp);
    attn_kernel<<<dim3(S, 3), 256, 0, stream>>>(kqvp, att1);
    linA_kernel<<<dim3(nb, 10), 256, 0, stream>>>(att1, linear1, linear2, part1, part2);
    lin3ab_kernel<<<dim3(4, 16), 256, 0, stream>>>(att1, linear3, tpart);
    combine_relu_kernel<<<nb, 256, 0, stream>>>(part1, y);

    // ---- Layer 2 (head 2 only) ----
    kqv_gemm_tiled<<<dim3(16, 3, 1), 256, 0, stream>>>(wq, wk, wv, 1, 2, y, kqvp);
    attn_kernel<<<dim3(S, 1), 256, 0, stream>>>(kqvp, att2);
    lin2c_kernel<<<dim3(nb, 2), 256, 0, stream>>>(att2, linear2, part2);
    combine_relu_kernel<<<nb, 256, 0, stream>>>(part2, y);

    // ---- Layer 3 (head 2 only, row 64 only) + lin3 tail ----
    kqv_gemm_tiled<<<dim3(16, 3, 1), 256, 0, stream>>>(wq, wk, wv, 2, 2, y, kqvp);
    attn3_lin3c_kernel<<<dim3(4, 8), 256, 0, stream>>>(kqvp, linear3, tpart);

    // ---- Final ----
    lin4_partial_kernel<<<dim3(2, KS4), 256, 0, stream>>>(tpart, linear4, upart);
    final_out_kernel<<<1, 512, 0, stream>>>(upart, linear5, out);
}